// Round 15
// baseline (253.305 us; speedup 1.0000x reference)
//
#include <hip/hip_runtime.h>
#include <math.h>

typedef __attribute__((ext_vector_type(8))) short short8;
typedef __attribute__((ext_vector_type(4))) float f32x4;
typedef __attribute__((ext_vector_type(4))) unsigned int u32x4;

static __device__ __forceinline__ unsigned short f2bf(float f) {
    union { float f; unsigned int u; } v; v.f = f;
    unsigned int r = v.u + 0x7fffu + ((v.u >> 16) & 1u);
    return (unsigned short)(r >> 16);
}
static __device__ __forceinline__ float bflo(unsigned int u) {
    union { unsigned int u; float f; } v; v.u = u << 16; return v.f;
}
static __device__ __forceinline__ float bfhi(unsigned int u) {
    union { unsigned int u; float f; } v; v.u = u & 0xffff0000u; return v.f;
}

// direct global->LDS, 16B per lane (dest = wave-uniform base + lane*16)
typedef __attribute__((address_space(1))) const unsigned int gu32;
typedef __attribute__((address_space(3))) unsigned int lu32;
static __device__ __forceinline__ void gload16(const void* g, void* l) {
    __builtin_amdgcn_global_load_lds((gu32*)g, (lu32*)l, 16, 0, 0);
}

// ---- fast zero ----
__global__ void zero_buf(u32x4* __restrict__ a, int n16)
{
    int i = blockIdx.x * blockDim.x + threadIdx.x;
    if (i < n16) a[i] = (u32x4){0u, 0u, 0u, 0u};
}

// ---- convert concat(h_v,h_t,h_tab) fp32 -> Xbf [N,384] bf16 ----
__global__ void convert_x(const float* __restrict__ hv, const float* __restrict__ ht,
                          const float* __restrict__ htab, unsigned short* __restrict__ X,
                          int total /* N*96 float4s */)
{
    int idx = blockIdx.x * blockDim.x + threadIdx.x;
    if (idx >= total) return;
    int r = idx / 96;
    int c4 = idx - r * 96;
    int seg = c4 >> 5;
    const float* s = (seg == 0) ? hv : (seg == 1) ? ht : htab;
    float4 v = ((const float4*)s)[(size_t)r * 32 + (c4 & 31)];
    ushort4 o;
    o.x = f2bf(v.x); o.y = f2bf(v.y); o.z = f2bf(v.z); o.w = f2bf(v.w);
    *(ushort4*)(X + (size_t)r * 384 + c4 * 4) = o;
}

// ---- convert + transpose all weights to bf16 Wt[n][k] ----
struct WDesc { const float* src; int K; int N; int dstoff; };
struct WPack { WDesc w[9]; };
__global__ void convert_w(WPack p, unsigned short* __restrict__ dst)
{
    WDesc d = p.w[blockIdx.y];
    int total = d.K * d.N;
    for (int i = blockIdx.x * blockDim.x + threadIdx.x; i < total;
         i += gridDim.x * blockDim.x) {
        int k = i / d.N, n = i - k * d.N;
        dst[d.dstoff + (size_t)n * d.K + k] = f2bf(d.src[i]);
    }
}

struct GemmP {
    const unsigned short* A; int lda;
    const unsigned short* Bt;
    const float* bias;
    float* Cf; int ldcf;
    unsigned short* Cb; int ldcb;
};
struct GemmP3 { GemmP q[3]; };

// ---------------------------------------------------------------------------
// gemm7: wide-tile bf16 GEMM (conv1/conv2). BM=128, BN=256, BK=64, 8 waves
// (2x4), global_load_lds staging (gemm5's proven K-loop), 48KB LDS, NP
// column panels with same-XCD y-fastest decode. Output bf16, line-coalesced.
// ---------------------------------------------------------------------------
template<int NP>
__global__ __launch_bounds__(512, 2) void gemm7(
    const unsigned short* __restrict__ A, int lda,
    const unsigned short* __restrict__ Bt,
    unsigned short* __restrict__ Cb, int ldcb,
    int M, int K)
{
    __shared__ __align__(16) unsigned short smem[(128 + 256) * 64];  // 48KB
    unsigned short* As = smem;                 // 128x64
    unsigned short* Bs = smem + 128 * 64;      // 256x64
    const int tid = threadIdx.x;
    const int lane = tid & 63;
    const int wid = tid >> 6;          // 0..7
    const int wr = wid >> 2;           // 0..1
    const int wc = wid & 3;            // 0..3
    const int bid = blockIdx.x;
    const int q = bid >> 3;
    const int m0 = ((bid & 7) + 8 * (q / NP)) * 128;
    const int n0 = (q % NP) * 256;

    const int lrow = lane >> 3;
    const int lchk = (lane & 7) ^ lrow;
    const unsigned short* gA[2];
    #pragma unroll
    for (int i = 0; i < 2; ++i) {
        int r = m0 + wid * 16 + i * 8 + lrow;
        if (r > M - 1) r = M - 1;
        gA[i] = A + (size_t)r * lda + lchk * 8;
    }
    const unsigned short* gB[4];
    #pragma unroll
    for (int i = 0; i < 4; ++i) {
        int r = n0 + wid * 32 + i * 8 + lrow;
        gB[i] = Bt + (size_t)r * K + lchk * 8;
    }
    unsigned short* lA = As + wid * 16 * 64;
    unsigned short* lB = Bs + wid * 32 * 64;

    f32x4 acc[4][4] = {};
    const int nt = K >> 6;
    for (int t = 0; t < nt; ++t) {
        __syncthreads();
        #pragma unroll
        for (int i = 0; i < 2; ++i) gload16(gA[i] + t * 64, lA + i * 8 * 64);
        #pragma unroll
        for (int i = 0; i < 4; ++i) gload16(gB[i] + t * 64, lB + i * 8 * 64);
        asm volatile("s_waitcnt vmcnt(0)" ::: "memory");
        __syncthreads();
        #pragma unroll
        for (int kk = 0; kk < 2; ++kk) {
            int g = kk * 4 + (lane >> 4);
            short8 a[4], b[4];
            #pragma unroll
            for (int mi = 0; mi < 4; ++mi) {
                int row = wr * 64 + mi * 16 + (lane & 15);
                a[mi] = *(const short8*)(As + row * 64 + ((g ^ (row & 7)) * 8));
            }
            #pragma unroll
            for (int ni = 0; ni < 4; ++ni) {
                int row = wc * 64 + ni * 16 + (lane & 15);
                b[ni] = *(const short8*)(Bs + row * 64 + ((g ^ (row & 7)) * 8));
            }
            #pragma unroll
            for (int mi = 0; mi < 4; ++mi)
                #pragma unroll
                for (int ni = 0; ni < 4; ++ni)
                    acc[mi][ni] = __builtin_amdgcn_mfma_f32_16x16x32_bf16(
                        a[mi], b[ni], acc[mi][ni], 0, 0, 0);
        }
    }

    // bf16 out: two half-tile (64x256) passes through LDS, full-line writes
    unsigned short* stage = smem;   // 64*256 shorts = 32KB
    #pragma unroll
    for (int half = 0; half < 2; ++half) {
        __syncthreads();
        if (wr == half) {
            #pragma unroll
            for (int mi = 0; mi < 4; ++mi)
                #pragma unroll
                for (int ni = 0; ni < 4; ++ni) {
                    int colL = wc * 64 + ni * 16 + (lane & 15);
                    #pragma unroll
                    for (int j = 0; j < 4; ++j) {
                        int rel = mi * 16 + ((lane >> 4) << 2) + j;
                        stage[rel * 256 + colL] = f2bf(acc[mi][ni][j]);
                    }
                }
        }
        __syncthreads();
        #pragma unroll
        for (int p = 0; p < 4; ++p) {
            int idx = p * 512 + tid;
            int r = idx >> 5, c8 = idx & 31;
            int grow = m0 + half * 64 + r;
            if (grow < M)
                *(u32x4*)(Cb + (size_t)grow * ldcb + n0 + c8 * 8) =
                    *(const u32x4*)(stage + r * 256 + c8 * 8);
        }
    }
}

struct GemmP3x { GemmP q[3]; };

// ---------------------------------------------------------------------------
// gemm4<1,1>: projections (m97 structure, BM=128, BN=128, 4 waves).
// bias + fp32 (nt, final) + bf16 out; blockIdx.z selects param set.
// ---------------------------------------------------------------------------
__global__ __launch_bounds__(256, 4) void gemm4p(GemmP3 ps, int M, int K)
{
    __shared__ __align__(16) unsigned short smem[128 * 64 * 2];  // 32KB
    unsigned short* As = smem;
    unsigned short* Bs = smem + 128 * 64;
    const GemmP P = ps.q[blockIdx.z];
    const int tid = threadIdx.x;
    const int lane = tid & 63;
    const int wid = tid >> 6;
    const int wr = wid >> 1, wc = wid & 1;
    const int m0 = blockIdx.x * 128;

    const int lrow = lane >> 3;
    const int lchk = (lane & 7) ^ lrow;
    const unsigned short* gA[4];
    #pragma unroll
    for (int i = 0; i < 4; ++i) {
        int r = m0 + wid * 32 + i * 8 + lrow;
        if (r > M - 1) r = M - 1;
        gA[i] = P.A + (size_t)r * P.lda + lchk * 8;
    }
    const unsigned short* gB[4];
    #pragma unroll
    for (int i = 0; i < 4; ++i) {
        int r = wid * 32 + i * 8 + lrow;
        gB[i] = P.Bt + (size_t)r * K + lchk * 8;
    }
    unsigned short* lA = As + wid * 32 * 64;
    unsigned short* lB = Bs + wid * 32 * 64;

    f32x4 acc[4][4] = {};
    const int nt = K >> 6;
    for (int t = 0; t < nt; ++t) {
        __syncthreads();
        #pragma unroll
        for (int i = 0; i < 4; ++i) gload16(gA[i] + t * 64, lA + i * 8 * 64);
        #pragma unroll
        for (int i = 0; i < 4; ++i) gload16(gB[i] + t * 64, lB + i * 8 * 64);
        asm volatile("s_waitcnt vmcnt(0)" ::: "memory");
        __syncthreads();
        #pragma unroll
        for (int kk = 0; kk < 2; ++kk) {
            int g = kk * 4 + (lane >> 4);
            short8 a[4], b[4];
            #pragma unroll
            for (int mi = 0; mi < 4; ++mi) {
                int row = wr * 64 + mi * 16 + (lane & 15);
                a[mi] = *(const short8*)(As + row * 64 + ((g ^ (row & 7)) * 8));
            }
            #pragma unroll
            for (int ni = 0; ni < 4; ++ni) {
                int row = wc * 64 + ni * 16 + (lane & 15);
                b[ni] = *(const short8*)(Bs + row * 64 + ((g ^ (row & 7)) * 8));
            }
            #pragma unroll
            for (int mi = 0; mi < 4; ++mi)
                #pragma unroll
                for (int ni = 0; ni < 4; ++ni)
                    acc[mi][ni] = __builtin_amdgcn_mfma_f32_16x16x32_bf16(
                        a[mi], b[ni], acc[mi][ni], 0, 0, 0);
        }
    }

    __syncthreads();
    #pragma unroll
    for (int mi = 0; mi < 4; ++mi)
        #pragma unroll
        for (int ni = 0; ni < 4; ++ni) {
            int colL = wc * 64 + ni * 16 + (lane & 15);
            float bv = P.bias[colL];
            #pragma unroll
            for (int j = 0; j < 4; ++j) {
                int rL = wr * 64 + mi * 16 + ((lane >> 4) << 2) + j;
                smem[rL * 128 + colL] = f2bf(acc[mi][ni][j] + bv);
            }
        }
    __syncthreads();
    #pragma unroll
    for (int p = 0; p < 8; ++p) {
        int idx = p * 256 + tid;
        int r = idx >> 4, c8 = idx & 15;
        int grow = m0 + r;
        if (grow < M)
            *(u32x4*)(P.Cb + (size_t)grow * P.ldcb + c8 * 8) =
                *(const u32x4*)(smem + r * 128 + c8 * 8);
    }
    float* stagef = (float*)smem;
    #pragma unroll
    for (int half = 0; half < 2; ++half) {
        __syncthreads();
        if (wr == half) {
            #pragma unroll
            for (int mi = 0; mi < 4; ++mi)
                #pragma unroll
                for (int ni = 0; ni < 4; ++ni) {
                    int colL = wc * 64 + ni * 16 + (lane & 15);
                    float bv = P.bias[colL];
                    #pragma unroll
                    for (int j = 0; j < 4; ++j) {
                        int rel = mi * 16 + ((lane >> 4) << 2) + j;
                        stagef[rel * 128 + colL] = acc[mi][ni][j] + bv;
                    }
                }
        }
        __syncthreads();
        #pragma unroll
        for (int p = 0; p < 8; ++p) {
            int idx = p * 256 + tid;
            int r = idx >> 5, c4 = idx & 31;
            int grow = m0 + half * 64 + r;
            if (grow < M)
                __builtin_nontemporal_store(
                    *(const f32x4*)(stagef + r * 128 + c4 * 4),
                    (f32x4*)(P.Cf + (size_t)grow * P.ldcf + c4 * 4));
        }
    }
}

// ---------------------------------------------------------------------------
// gemm5: classifier (proven). BM=128, BN=256, 8 waves, fused logits.
// ---------------------------------------------------------------------------
__global__ __launch_bounds__(512, 2) void gemm5(
    const unsigned short* __restrict__ A,
    const unsigned short* __restrict__ Bt,
    const float* __restrict__ bias,
    const unsigned short* __restrict__ Wc2t,
    const float* __restrict__ bc2,
    float* __restrict__ logits,
    int M, int K)
{
    __shared__ __align__(16) unsigned short smem[128 * 256];  // 64KB
    unsigned short* As = smem;
    unsigned short* Bs = smem + 128 * 64;
    const int tid = threadIdx.x;
    const int lane = tid & 63;
    const int wid = tid >> 6;
    const int wr = wid >> 2;
    const int wc = wid & 3;
    const int m0 = blockIdx.x * 128;

    const int lrow = lane >> 3;
    const int lchk = (lane & 7) ^ lrow;
    const unsigned short* gA[2];
    #pragma unroll
    for (int i = 0; i < 2; ++i) {
        int r = m0 + wid * 16 + i * 8 + lrow;
        if (r > M - 1) r = M - 1;
        gA[i] = A + (size_t)r * K + lchk * 8;
    }
    const unsigned short* gB[4];
    #pragma unroll
    for (int i = 0; i < 4; ++i) {
        int r = wid * 32 + i * 8 + lrow;
        gB[i] = Bt + (size_t)r * K + lchk * 8;
    }
    unsigned short* lA = As + wid * 16 * 64;
    unsigned short* lB = Bs + wid * 32 * 64;

    f32x4 acc[4][4] = {};
    const int nt = K >> 6;   // 8
    for (int t = 0; t < nt; ++t) {
        __syncthreads();
        #pragma unroll
        for (int i = 0; i < 2; ++i) gload16(gA[i] + t * 64, lA + i * 8 * 64);
        #pragma unroll
        for (int i = 0; i < 4; ++i) gload16(gB[i] + t * 64, lB + i * 8 * 64);
        asm volatile("s_waitcnt vmcnt(0)" ::: "memory");
        __syncthreads();
        #pragma unroll
        for (int kk = 0; kk < 2; ++kk) {
            int g = kk * 4 + (lane >> 4);
            short8 a[4], b[4];
            #pragma unroll
            for (int mi = 0; mi < 4; ++mi) {
                int row = wr * 64 + mi * 16 + (lane & 15);
                a[mi] = *(const short8*)(As + row * 64 + ((g ^ (row & 7)) * 8));
            }
            #pragma unroll
            for (int ni = 0; ni < 4; ++ni) {
                int row = wc * 64 + ni * 16 + (lane & 15);
                b[ni] = *(const short8*)(Bs + row * 64 + ((g ^ (row & 7)) * 8));
            }
            #pragma unroll
            for (int mi = 0; mi < 4; ++mi)
                #pragma unroll
                for (int ni = 0; ni < 4; ++ni)
                    acc[mi][ni] = __builtin_amdgcn_mfma_f32_16x16x32_bf16(
                        a[mi], b[ni], acc[mi][ni], 0, 0, 0);
        }
    }

    __syncthreads();
    #pragma unroll
    for (int mi = 0; mi < 4; ++mi)
        #pragma unroll
        for (int ni = 0; ni < 4; ++ni) {
            int colL = wc * 64 + ni * 16 + (lane & 15);
            float bv = bias[colL];
            #pragma unroll
            for (int j = 0; j < 4; ++j) {
                int rL = wr * 64 + mi * 16 + ((lane >> 4) << 2) + j;
                float x = fmaxf(acc[mi][ni][j] + bv, 0.0f);
                int c8 = colL >> 3;
                smem[rL * 256 + ((c8 ^ (rL & 7)) * 8) + (colL & 7)] = f2bf(x);
            }
        }
    __syncthreads();
    f32x4 lacc = {0.f, 0.f, 0.f, 0.f};
    int rL = wid * 16 + (lane & 15);
    #pragma unroll
    for (int k0 = 0; k0 < 256; k0 += 32) {
        int c8 = (k0 >> 3) + (lane >> 4);
        short8 a = *(const short8*)(smem + rL * 256 + ((c8 ^ (rL & 7)) * 8));
        short8 b = *(const short8*)(Wc2t + (lane & 15) * 256 + k0 + (lane >> 4) * 8);
        lacc = __builtin_amdgcn_mfma_f32_16x16x32_bf16(a, b, lacc, 0, 0, 0);
    }
    int colL = lane & 15;
    if (colL < 14) {
        float bb = bc2[colL];
        #pragma unroll
        for (int j = 0; j < 4; ++j) {
            int r = m0 + wid * 16 + (lane >> 4) * 4 + j;
            if (r < M)
                __builtin_nontemporal_store(lacc[j] + bb,
                    logits + (size_t)r * 14 + colL);
        }
    }
}

// ---- CSR build ----
__global__ void count_deg(const int* __restrict__ dst, int* __restrict__ deg, int E)
{
    int e = blockIdx.x * blockDim.x + threadIdx.x;
    if (e < E) atomicAdd(&deg[dst[e]], 1);
}

__global__ __launch_bounds__(1024) void scan_part(
    const int* __restrict__ deg, int* __restrict__ off, int* __restrict__ sums, int N)
{
    __shared__ int buf[1024];
    int i = blockIdx.x * 1024 + threadIdx.x;
    int v = (i < N) ? deg[i] : 0;
    buf[threadIdx.x] = v;
    __syncthreads();
    #pragma unroll
    for (int o = 1; o < 1024; o <<= 1) {
        int t = (threadIdx.x >= o) ? buf[threadIdx.x - o] : 0;
        __syncthreads();
        buf[threadIdx.x] += t;
        __syncthreads();
    }
    if (i < N) off[i] = buf[threadIdx.x] - v;
    if (threadIdx.x == 1023) sums[blockIdx.x] = buf[1023];
}

__global__ void scan_sums(int* __restrict__ sums, int* __restrict__ offN, int nb)
{
    int lane = threadIdx.x;
    int v = (lane < nb) ? sums[lane] : 0;
    int incl = v;
    #pragma unroll
    for (int o = 1; o < 64; o <<= 1) {
        int t = __shfl_up(incl, o);
        if (lane >= o) incl += t;
    }
    if (lane < nb) sums[lane] = incl - v;
    if (lane == 63) *offN = incl;
}

__global__ __launch_bounds__(1024) void scan_add(
    const int* __restrict__ sums, int* __restrict__ off,
    int* __restrict__ cursor, int N)
{
    int i = blockIdx.x * 1024 + threadIdx.x;
    if (i < N) {
        int v = off[i] + sums[blockIdx.x];
        off[i] = v;
        cursor[i] = v;
    }
}

__global__ void fill_csr(const int* __restrict__ src, const int* __restrict__ dst,
                         int* __restrict__ cursor, int* __restrict__ csr, int E)
{
    int e = blockIdx.x * blockDim.x + threadIdx.x;
    if (e < E) {
        int p = atomicAdd(&cursor[dst[e]], 1);
        csr[p] = src[e];
    }
}

// ---- conv1 epilogue: h_g1 = relu(mean_nbr(y1.l)+b+y1.r) -> bf16 [N,256] ----
__global__ __launch_bounds__(256) void sage1_gather(
    const unsigned short* __restrict__ y1,
    const int* __restrict__ off, const int* __restrict__ csr,
    const float* __restrict__ b, unsigned short* __restrict__ out, int N)
{
    int lane = threadIdx.x & 63;
    int node = blockIdx.x * 4 + (threadIdx.x >> 6);
    if (node >= N) return;
    int s = off[node], e = off[node + 1];
    int half = lane >> 5, l32 = lane & 31;
    float a[8] = {};
    int p = s + half;
    for (; p + 6 < e; p += 8) {
        int j0 = csr[p],     j1 = csr[p + 2];
        int j2 = csr[p + 4], j3 = csr[p + 6];
        uint4 v0 = *(const uint4*)(y1 + (size_t)j0 * 512 + l32 * 8);
        uint4 v1 = *(const uint4*)(y1 + (size_t)j1 * 512 + l32 * 8);
        uint4 v2 = *(const uint4*)(y1 + (size_t)j2 * 512 + l32 * 8);
        uint4 v3 = *(const uint4*)(y1 + (size_t)j3 * 512 + l32 * 8);
        a[0] += bflo(v0.x); a[1] += bfhi(v0.x); a[2] += bflo(v0.y); a[3] += bfhi(v0.y);
        a[4] += bflo(v0.z); a[5] += bfhi(v0.z); a[6] += bflo(v0.w); a[7] += bfhi(v0.w);
        a[0] += bflo(v1.x); a[1] += bfhi(v1.x); a[2] += bflo(v1.y); a[3] += bfhi(v1.y);
        a[4] += bflo(v1.z); a[5] += bfhi(v1.z); a[6] += bflo(v1.w); a[7] += bfhi(v1.w);
        a[0] += bflo(v2.x); a[1] += bfhi(v2.x); a[2] += bflo(v2.y); a[3] += bfhi(v2.y);
        a[4] += bflo(v2.z); a[5] += bfhi(v2.z); a[6] += bflo(v2.w); a[7] += bfhi(v2.w);
        a[0] += bflo(v3.x); a[1] += bfhi(v3.x); a[2] += bflo(v3.y); a[3] += bfhi(v3.y);
        a[4] += bflo(v3.z); a[5] += bfhi(v3.z); a[6] += bflo(v3.w); a[7] += bfhi(v3.w);
    }
    for (; p + 2 < e; p += 4) {
        int j0 = csr[p], j1 = csr[p + 2];
        uint4 v0 = *(const uint4*)(y1 + (size_t)j0 * 512 + l32 * 8);
        uint4 v1 = *(const uint4*)(y1 + (size_t)j1 * 512 + l32 * 8);
        a[0] += bflo(v0.x); a[1] += bfhi(v0.x); a[2] += bflo(v0.y); a[3] += bfhi(v0.y);
        a[4] += bflo(v0.z); a[5] += bfhi(v0.z); a[6] += bflo(v0.w); a[7] += bfhi(v0.w);
        a[0] += bflo(v1.x); a[1] += bfhi(v1.x); a[2] += bflo(v1.y); a[3] += bfhi(v1.y);
        a[4] += bflo(v1.z); a[5] += bfhi(v1.z); a[6] += bflo(v1.w); a[7] += bfhi(v1.w);
    }
    for (; p < e; p += 2) {
        int j = csr[p];
        uint4 v = *(const uint4*)(y1 + (size_t)j * 512 + l32 * 8);
        a[0] += bflo(v.x); a[1] += bfhi(v.x); a[2] += bflo(v.y); a[3] += bfhi(v.y);
        a[4] += bflo(v.z); a[5] += bfhi(v.z); a[6] += bflo(v.w); a[7] += bfhi(v.w);
    }
    #pragma unroll
    for (int i = 0; i < 8; ++i) a[i] += __shfl_xor(a[i], 32);
    if (half == 0) {
        float inv = (e > s) ? 1.0f / (float)(e - s) : 1.0f;
        uint4 rv = *(const uint4*)(y1 + (size_t)node * 512 + 256 + l32 * 8);
        float4 b0 = ((const float4*)b)[l32 * 2];
        float4 b1 = ((const float4*)b)[l32 * 2 + 1];
        float r[8] = {bflo(rv.x), bfhi(rv.x), bflo(rv.y), bfhi(rv.y),
                      bflo(rv.z), bfhi(rv.z), bflo(rv.w), bfhi(rv.w)};
        float bb[8] = {b0.x, b0.y, b0.z, b0.w, b1.x, b1.y, b1.z, b1.w};
        u32x4 vv;
        #pragma unroll
        for (int i = 0; i < 4; ++i) {
            unsigned int lo = f2bf(fmaxf(a[2*i]   * inv + bb[2*i]   + r[2*i],   0.f));
            unsigned int hi = f2bf(fmaxf(a[2*i+1] * inv + bb[2*i+1] + r[2*i+1], 0.f));
            vv[i] = lo | (hi << 16);
        }
        *(u32x4*)(out + (size_t)node * 256 + l32 * 8) = vv;
    }
}

// ---- conv2 epilogue: h_g = l2norm(mean+b+root) -> bf16 (cls_bf col 384) ----
__global__ __launch_bounds__(256) void sage2_gather_norm(
    const unsigned short* __restrict__ y2,
    const int* __restrict__ off, const int* __restrict__ csr,
    const float* __restrict__ b, unsigned short* __restrict__ outb, int N)
{
    int lane = threadIdx.x & 63;
    int node = blockIdx.x * 4 + (threadIdx.x >> 6);
    if (node >= N) return;
    int s = off[node], e = off[node + 1];
    int grp = lane >> 4, l16 = lane & 15;
    float a[8] = {};
    int p = s + grp;
    for (; p + 4 < e; p += 8) {
        int j0 = csr[p], j1 = csr[p + 4];
        uint4 v0 = *(const uint4*)(y2 + (size_t)j0 * 256 + l16 * 8);
        uint4 v1 = *(const uint4*)(y2 + (size_t)j1 * 256 + l16 * 8);
        a[0] += bflo(v0.x); a[1] += bfhi(v0.x); a[2] += bflo(v0.y); a[3] += bfhi(v0.y);
        a[4] += bflo(v0.z); a[5] += bfhi(v0.z); a[6] += bflo(v0.w); a[7] += bfhi(v0.w);
        a[0] += bflo(v1.x); a[1] += bfhi(v1.x); a[2] += bflo(v1.y); a[3] += bfhi(v1.y);
        a[4] += bflo(v1.z); a[5] += bfhi(v1.z); a[6] += bflo(v1.w); a[7] += bfhi(v1.w);
    }
    for (; p < e; p += 4) {
        int j = csr[p];
        uint4 v = *(const uint4*)(y2 + (size_t)j * 256 + l16 * 8);
        a[0] += bflo(v.x); a[1] += bfhi(v.x); a[2] += bflo(v.y); a[3] += bfhi(v.y);
        a[4] += bflo(v.z); a[5] += bfhi(v.z); a[6] += bflo(v.w); a[7] += bfhi(v.w);
    }
    #pragma unroll
    for (int i = 0; i < 8; ++i) {
        a[i] += __shfl_xor(a[i], 16);
        a[i] += __shfl_xor(a[i], 32);
    }
    if (grp == 0) {
        float inv = (e > s) ? 1.0f / (float)(e - s) : 1.0f;
        uint4 rv = *(const uint4*)(y2 + (size_t)node * 256 + 128 + l16 * 8);
        float4 b0 = ((const float4*)b)[l16 * 2];
        float4 b1 = ((const float4*)b)[l16 * 2 + 1];
        float r[8] = {bflo(rv.x), bfhi(rv.x), bflo(rv.y), bfhi(rv.y),
                      bflo(rv.z), bfhi(rv.z), bflo(rv.w), bfhi(rv.w)};
        float bb[8] = {b0.x, b0.y, b0.z, b0.w, b1.x, b1.y, b1.z, b1.w};
        float h[8];
        float ss = 0.f;
        #pragma unroll
        for (int i = 0; i < 8; ++i) {
            h[i] = a[i] * inv + bb[i] + r[i];
            ss += h[i] * h[i];
        }
        ss += __shfl_xor(ss, 1);
        ss += __shfl_xor(ss, 2);
        ss += __shfl_xor(ss, 4);
        ss += __shfl_xor(ss, 8);
        float sc = 1.0f / fmaxf(sqrtf(ss), 1e-12f);
        u32x4 vv;
        #pragma unroll
        for (int i = 0; i < 4; ++i) {
            unsigned int lo = f2bf(h[2*i] * sc);
            unsigned int hi = f2bf(h[2*i+1] * sc);
            vv[i] = lo | (hi << 16);
        }
        *(u32x4*)(outb + (size_t)node * 512 + l16 * 8) = vv;
    }
}

extern "C" void kernel_launch(void* const* d_in, const int* in_sizes, int n_in,
                              void* d_out, int out_size, void* d_ws, size_t ws_size,
                              hipStream_t stream)
{
    const float* h_v   = (const float*)d_in[0];
    const float* h_t   = (const float*)d_in[1];
    const float* h_tab = (const float*)d_in[2];
    const int*   eidx  = (const int*)d_in[3];
    const float* W1l = (const float*)d_in[4];
    const float* W1r = (const float*)d_in[5];
    const float* b1g = (const float*)d_in[6];
    const float* W2l = (const float*)d_in[7];
    const float* W2r = (const float*)d_in[8];
    const float* b2g = (const float*)d_in[9];
    const float* Wsh = (const float*)d_in[10];
    const float* bsh = (const float*)d_in[11];
    const float* Wst = (const float*)d_in[12];
    const float* bst = (const float*)d_in[13];
    const float* Wstab = (const float*)d_in[14];
    const float* bstab = (const float*)d_in[15];
    const float* Wc1 = (const float*)d_in[16];
    const float* bc1 = (const float*)d_in[17];
    const float* Wc2 = (const float*)d_in[18];
    const float* bc2 = (const float*)d_in[19];

    const int N = in_sizes[0] / 128;      // 50000
    const int E = in_sizes[3] / 2;        // 500000
    const int* src = eidx;
    const int* dst = eidx + E;

    // ---- workspace layout ----
    int* deg    = (int*)d_ws;
    int* off    = deg + N;
    int* cursor = off + N + 1;
    int* csr    = cursor + N;
    int* sums   = csr + E;
    size_t int_bytes = ((size_t)3 * N + 1 + E + 64) * 4;
    unsigned short* Wt = (unsigned short*)((char*)d_ws + ((int_bytes + 255) & ~(size_t)255));
    const int oW1l = 0;                    // 256*384
    const int oW1r = oW1l + 98304;
    const int oW2l = oW1r + 98304;         // 128*256
    const int oW2r = oW2l + 32768;
    const int oWsh = oW2r + 32768;         // 128*128
    const int oWst = oWsh + 16384;
    const int oWstab = oWst + 16384;
    const int oWc1 = oWstab + 16384;       // 256*512
    const int oWc2t = oWc1 + 131072;       // 16*256 (rows 14,15 zero)
    const int wtotal = oWc2t + 4096;

    unsigned short* Xbf   = Wt + wtotal;                  // [N,384]
    unsigned short* bufY  = Xbf + (size_t)N * 384;        // y1 [N,512] -> cls_bf
    unsigned short* bufH  = bufY + (size_t)N * 512;       // hg1 [N,256]
    unsigned short* bufY2 = bufH + (size_t)N * 256;       // y2 [N,256]

    float* out    = (float*)d_out;
    float* logits = out;
    float* z_sh   = out + (size_t)N * 14;
    float* z_t    = z_sh + (size_t)N * 128;
    float* z_tab  = z_t + (size_t)N * 128;

    const int gx = (N + 127) / 128;   // 391
    const int gxp = (gx + 7) & ~7;    // 392: multiple of 8 for XCD decode
    const int nb = (N + 1023) / 1024; // 49

    // ---- CSR build ----
    {
        int n16 = (N * 4) / 16;
        zero_buf<<<(n16 + 255) / 256, 256, 0, stream>>>((u32x4*)deg, n16);
        zero_buf<<<2, 256, 0, stream>>>((u32x4*)(Wt + oWc2t), 512);
    }
    count_deg<<<(E + 255) / 256, 256, 0, stream>>>(dst, deg, E);
    scan_part<<<nb, 1024, 0, stream>>>(deg, off, sums, N);
    scan_sums<<<1, 64, 0, stream>>>(sums, off + N, nb);
    scan_add<<<nb, 1024, 0, stream>>>(sums, off, cursor, N);
    fill_csr<<<(E + 255) / 256, 256, 0, stream>>>(src, dst, cursor, csr, E);

    // ---- conversions ----
    convert_x<<<(N * 96 + 255) / 256, 256, 0, stream>>>(h_v, h_t, h_tab, Xbf, N * 96);
    WPack p;
    p.w[0] = {W1l, 384, 256, oW1l};     p.w[1] = {W1r, 384, 256, oW1r};
    p.w[2] = {W2l, 256, 128, oW2l};     p.w[3] = {W2r, 256, 128, oW2r};
    p.w[4] = {Wsh, 128, 128, oWsh};     p.w[5] = {Wst, 128, 128, oWst};
    p.w[6] = {Wstab, 128, 128, oWstab}; p.w[7] = {Wc1, 512, 256, oWc1};
    p.w[8] = {Wc2, 256, 14, oWc2t};
    convert_w<<<dim3(128, 9), 256, 0, stream>>>(p, Wt);

    // ---- conv1: [N,384] x [384, 512(l|r)] -> y1 bf16 (2 wide panels) ----
    unsigned short* y1 = bufY;
    gemm7<2><<<dim3(gxp * 2), 512, 0, stream>>>(Xbf, 384, Wt + oW1l, y1, 512, N, 384);

    // ---- conv1 gather -> h_g1 bf16 [N,256] ----
    sage1_gather<<<(N + 3) / 4, 256, 0, stream>>>(y1, off, csr, b1g, bufH, N);

    // ---- conv2: [N,256] x [256, 256(l|r)] -> y2 bf16 (1 wide panel) ----
    gemm7<1><<<dim3(gxp), 512, 0, stream>>>(bufH, 256, Wt + oW2l, bufY2, 256, N, 256);

    // ---- conv2 gather + l2norm -> h_g bf16 (cls_bf col 384) ----
    unsigned short* cls_bf = bufY;  // y1 dead
    sage2_gather_norm<<<(N + 3) / 4, 256, 0, stream>>>(bufY2, off, csr, b2g,
        cls_bf + 384, N);

    // ---- 3 projections in one launch: fp32 -> d_out, bf16 -> cls_bf ----
    {
        GemmP3 g{};
        g.q[0] = {cls_bf + 384, 512, Wt + oWsh,   bsh,   z_sh,  128, cls_bf + 0,   512};
        g.q[1] = {Xbf + 128,    384, Wt + oWst,   bst,   z_t,   128, cls_bf + 128, 512};
        g.q[2] = {Xbf + 256,    384, Wt + oWstab, bstab, z_tab, 128, cls_bf + 256, 512};
        gemm4p<<<dim3(gxp, 1, 3), 256, 0, stream>>>(g, N, 128);
    }

    // ---- classifier: [N,512]x[512,256] + relu + fused logits ----
    gemm5<<<dim3(gxp), 512, 0, stream>>>(cls_bf, Wt + oWc1, bc1,
        Wt + oWc2t, bc2, logits, N, 512);
}

// Round 16
// 245.415 us; speedup vs baseline: 1.0321x; 1.0321x over previous
//
#include <hip/hip_runtime.h>
#include <math.h>

typedef __attribute__((ext_vector_type(8))) short short8;
typedef __attribute__((ext_vector_type(4))) float f32x4;
typedef __attribute__((ext_vector_type(4))) unsigned int u32x4;

static __device__ __forceinline__ unsigned short f2bf(float f) {
    union { float f; unsigned int u; } v; v.f = f;
    unsigned int r = v.u + 0x7fffu + ((v.u >> 16) & 1u);
    return (unsigned short)(r >> 16);
}
static __device__ __forceinline__ float bflo(unsigned int u) {
    union { unsigned int u; float f; } v; v.u = u << 16; return v.f;
}
static __device__ __forceinline__ float bfhi(unsigned int u) {
    union { unsigned int u; float f; } v; v.u = u & 0xffff0000u; return v.f;
}

// direct global->LDS, 16B per lane (dest = wave-uniform base + lane*16)
typedef __attribute__((address_space(1))) const unsigned int gu32;
typedef __attribute__((address_space(3))) unsigned int lu32;
static __device__ __forceinline__ void gload16(const void* g, void* l) {
    __builtin_amdgcn_global_load_lds((gu32*)g, (lu32*)l, 16, 0, 0);
}

struct WDesc { const float* src; int K; int N; int dstoff; };
struct WPack { WDesc w[9]; };

// ---------------------------------------------------------------------------
// prep: merged {zero deg | zero Wc2t pad rows | convert_x | convert_w}.
// All block ranges are mutually independent (no intra-launch ordering needed).
// Wc2t: only rows 14,15 are zeroed here (rows 0..13 written by convert_w).
// ---------------------------------------------------------------------------
__global__ __launch_bounds__(256) void prep(
    const float* __restrict__ hv, const float* __restrict__ ht,
    const float* __restrict__ htab, unsigned short* __restrict__ X, int N,
    WPack p, unsigned short* __restrict__ Wt,
    int* __restrict__ deg, unsigned short* __restrict__ wc2pad)
{
    const int b = blockIdx.x;
    const int ndeg16 = (N + 3) / 4;            // deg as u32x4 count (N ints)
    const int ZB = (ndeg16 + 255) / 256;       // 50
    const int XB = (N * 96 + 255) / 256;       // convert_x blocks

    if (b < ZB) {
        int i = b * 256 + threadIdx.x;
        if (i < ndeg16) ((u32x4*)deg)[i] = (u32x4){0u, 0u, 0u, 0u};
    } else if (b < ZB + 1) {
        // zero Wc2t rows 14,15: 512 shorts = 64 u32x4
        int i = threadIdx.x;
        if (i < 64) ((u32x4*)wc2pad)[i] = (u32x4){0u, 0u, 0u, 0u};
    } else if (b < ZB + 1 + XB) {
        int idx = (b - ZB - 1) * 256 + threadIdx.x;
        if (idx < N * 96) {
            int r = idx / 96;
            int c4 = idx - r * 96;
            int seg = c4 >> 5;
            const float* s = (seg == 0) ? hv : (seg == 1) ? ht : htab;
            float4 v = ((const float4*)s)[(size_t)r * 32 + (c4 & 31)];
            ushort4 o;
            o.x = f2bf(v.x); o.y = f2bf(v.y); o.z = f2bf(v.z); o.w = f2bf(v.w);
            *(ushort4*)(X + (size_t)r * 384 + c4 * 4) = o;
        }
    } else {
        int wb = b - ZB - 1 - XB;              // 0..575
        int wi = wb >> 6;                      // weight 0..8
        int lb = wb & 63;
        WDesc d = p.w[wi];
        int total = d.K * d.N;
        for (int i = lb * 256 + threadIdx.x; i < total; i += 64 * 256) {
            int k = i / d.N, n = i - k * d.N;
            Wt[d.dstoff + (size_t)n * d.K + k] = f2bf(d.src[i]);
        }
    }
}

struct GemmP {
    const unsigned short* A; int lda;
    const unsigned short* Bt;
    const float* bias;
    float* Cf; int ldcf;
    unsigned short* Cb; int ldcb;
};
struct GemmP3 { GemmP q[3]; };

// ---------------------------------------------------------------------------
// gemm4: m97-structure bf16 GEMM. 128x128 tile, BK=64, 4 waves (2x2),
// global_load_lds(16B) staging with source-side XOR swizzle, single LDS
// buffer, 2 barriers/K-step. NP column panels, same-XCD y-fastest decode.
// MODE 0: bf16 out. MODE 1: bias + fp32 (nt, final) + bf16 out (z-grid).
// ---------------------------------------------------------------------------
template<int MODE, int NP>
__global__ __launch_bounds__(256, 4) void gemm4(GemmP3 ps, int M, int K)
{
    __shared__ __align__(16) unsigned short smem[128 * 64 * 2];  // As|Bs 32KB
    unsigned short* As = smem;
    unsigned short* Bs = smem + 128 * 64;
    const GemmP P = ps.q[(MODE == 1) ? blockIdx.z : 0];
    const int tid = threadIdx.x;
    const int lane = tid & 63;
    const int wid = tid >> 6;          // 0..3
    const int wr = wid >> 1, wc = wid & 1;
    const int bid = blockIdx.x;
    const int q = bid >> 3;
    const int m0 = ((bid & 7) + 8 * (q / NP)) * 128;
    const int n0 = (q % NP) * 128;

    const int lrow = lane >> 3;              // 0..7
    const int lchk = (lane & 7) ^ lrow;      // src 16B-chunk (rows 8-aligned)
    const unsigned short* gA[4];
    #pragma unroll
    for (int i = 0; i < 4; ++i) {
        int r = m0 + wid * 32 + i * 8 + lrow;
        if (r > M - 1) r = M - 1;
        gA[i] = P.A + (size_t)r * P.lda + lchk * 8;
    }
    const unsigned short* gB[4];
    #pragma unroll
    for (int i = 0; i < 4; ++i) {
        int r = n0 + wid * 32 + i * 8 + lrow;
        gB[i] = P.Bt + (size_t)r * K + lchk * 8;
    }
    unsigned short* lA = As + wid * 32 * 64;
    unsigned short* lB = Bs + wid * 32 * 64;

    f32x4 acc[4][4] = {};
    const int nt = K >> 6;
    for (int t = 0; t < nt; ++t) {
        __syncthreads();
        #pragma unroll
        for (int i = 0; i < 4; ++i) gload16(gA[i] + t * 64, lA + i * 8 * 64);
        #pragma unroll
        for (int i = 0; i < 4; ++i) gload16(gB[i] + t * 64, lB + i * 8 * 64);
        asm volatile("s_waitcnt vmcnt(0)" ::: "memory");
        __syncthreads();
        #pragma unroll
        for (int kk = 0; kk < 2; ++kk) {
            int g = kk * 4 + (lane >> 4);
            short8 a[4], b[4];
            #pragma unroll
            for (int mi = 0; mi < 4; ++mi) {
                int row = wr * 64 + mi * 16 + (lane & 15);
                a[mi] = *(const short8*)(As + row * 64 + ((g ^ (row & 7)) * 8));
            }
            #pragma unroll
            for (int ni = 0; ni < 4; ++ni) {
                int row = wc * 64 + ni * 16 + (lane & 15);
                b[ni] = *(const short8*)(Bs + row * 64 + ((g ^ (row & 7)) * 8));
            }
            #pragma unroll
            for (int mi = 0; mi < 4; ++mi)
                #pragma unroll
                for (int ni = 0; ni < 4; ++ni)
                    acc[mi][ni] = __builtin_amdgcn_mfma_f32_16x16x32_bf16(
                        a[mi], b[ni], acc[mi][ni], 0, 0, 0);
        }
    }

    if (MODE == 0) {
        unsigned short* stage = smem;   // 64x128 shorts per half
        #pragma unroll
        for (int half = 0; half < 2; ++half) {
            __syncthreads();
            if (wr == half) {
                #pragma unroll
                for (int mi = 0; mi < 4; ++mi)
                    #pragma unroll
                    for (int ni = 0; ni < 4; ++ni) {
                        int colL = wc * 64 + ni * 16 + (lane & 15);
                        #pragma unroll
                        for (int j = 0; j < 4; ++j) {
                            int rel = mi * 16 + ((lane >> 4) << 2) + j;
                            stage[rel * 128 + colL] = f2bf(acc[mi][ni][j]);
                        }
                    }
            }
            __syncthreads();
            #pragma unroll
            for (int pq = 0; pq < 4; ++pq) {
                int idx = pq * 256 + tid;
                int r = idx >> 4, c8 = idx & 15;
                int grow = m0 + half * 64 + r;
                if (grow < M)
                    *(u32x4*)(P.Cb + (size_t)grow * P.ldcb + n0 + c8 * 8) =
                        *(const u32x4*)(stage + r * 128 + c8 * 8);
            }
        }
    }

    if (MODE == 1) {
        __syncthreads();
        #pragma unroll
        for (int mi = 0; mi < 4; ++mi)
            #pragma unroll
            for (int ni = 0; ni < 4; ++ni) {
                int colL = wc * 64 + ni * 16 + (lane & 15);
                float bv = P.bias[colL];
                #pragma unroll
                for (int j = 0; j < 4; ++j) {
                    int rL = wr * 64 + mi * 16 + ((lane >> 4) << 2) + j;
                    smem[rL * 128 + colL] = f2bf(acc[mi][ni][j] + bv);
                }
            }
        __syncthreads();
        #pragma unroll
        for (int pq = 0; pq < 8; ++pq) {
            int idx = pq * 256 + tid;
            int r = idx >> 4, c8 = idx & 15;
            int grow = m0 + r;
            if (grow < M)
                *(u32x4*)(P.Cb + (size_t)grow * P.ldcb + n0 + c8 * 8) =
                    *(const u32x4*)(smem + r * 128 + c8 * 8);
        }
        float* stagef = (float*)smem;
        #pragma unroll
        for (int half = 0; half < 2; ++half) {
            __syncthreads();
            if (wr == half) {
                #pragma unroll
                for (int mi = 0; mi < 4; ++mi)
                    #pragma unroll
                    for (int ni = 0; ni < 4; ++ni) {
                        int colL = wc * 64 + ni * 16 + (lane & 15);
                        float bv = P.bias[colL];
                        #pragma unroll
                        for (int j = 0; j < 4; ++j) {
                            int rel = mi * 16 + ((lane >> 4) << 2) + j;
                            stagef[rel * 128 + colL] = acc[mi][ni][j] + bv;
                        }
                    }
            }
            __syncthreads();
            #pragma unroll
            for (int pq = 0; pq < 8; ++pq) {
                int idx = pq * 256 + tid;
                int r = idx >> 5, c4 = idx & 31;
                int grow = m0 + half * 64 + r;
                if (grow < M)
                    __builtin_nontemporal_store(
                        *(const f32x4*)(stagef + r * 128 + c4 * 4),
                        (f32x4*)(P.Cf + (size_t)grow * P.ldcf + n0 + c4 * 4));
            }
        }
    }
}

// ---------------------------------------------------------------------------
// gemm5: classifier. BM=128, BN=256, BK=64, 8 waves, global_load_lds
// staging, fused bias+relu -> LDS hidden -> logits GEMM.
// ---------------------------------------------------------------------------
__global__ __launch_bounds__(512, 2) void gemm5(
    const unsigned short* __restrict__ A,
    const unsigned short* __restrict__ Bt,
    const float* __restrict__ bias,
    const unsigned short* __restrict__ Wc2t,
    const float* __restrict__ bc2,
    float* __restrict__ logits,
    int M, int K)
{
    __shared__ __align__(16) unsigned short smem[128 * 256];  // 64KB
    unsigned short* As = smem;
    unsigned short* Bs = smem + 128 * 64;
    const int tid = threadIdx.x;
    const int lane = tid & 63;
    const int wid = tid >> 6;
    const int wr = wid >> 2;
    const int wc = wid & 3;
    const int m0 = blockIdx.x * 128;

    const int lrow = lane >> 3;
    const int lchk = (lane & 7) ^ lrow;
    const unsigned short* gA[2];
    #pragma unroll
    for (int i = 0; i < 2; ++i) {
        int r = m0 + wid * 16 + i * 8 + lrow;
        if (r > M - 1) r = M - 1;
        gA[i] = A + (size_t)r * K + lchk * 8;
    }
    const unsigned short* gB[4];
    #pragma unroll
    for (int i = 0; i < 4; ++i) {
        int r = wid * 32 + i * 8 + lrow;
        gB[i] = Bt + (size_t)r * K + lchk * 8;
    }
    unsigned short* lA = As + wid * 16 * 64;
    unsigned short* lB = Bs + wid * 32 * 64;

    f32x4 acc[4][4] = {};
    const int nt = K >> 6;   // 8
    for (int t = 0; t < nt; ++t) {
        __syncthreads();
        #pragma unroll
        for (int i = 0; i < 2; ++i) gload16(gA[i] + t * 64, lA + i * 8 * 64);
        #pragma unroll
        for (int i = 0; i < 4; ++i) gload16(gB[i] + t * 64, lB + i * 8 * 64);
        asm volatile("s_waitcnt vmcnt(0)" ::: "memory");
        __syncthreads();
        #pragma unroll
        for (int kk = 0; kk < 2; ++kk) {
            int g = kk * 4 + (lane >> 4);
            short8 a[4], b[4];
            #pragma unroll
            for (int mi = 0; mi < 4; ++mi) {
                int row = wr * 64 + mi * 16 + (lane & 15);
                a[mi] = *(const short8*)(As + row * 64 + ((g ^ (row & 7)) * 8));
            }
            #pragma unroll
            for (int ni = 0; ni < 4; ++ni) {
                int row = wc * 64 + ni * 16 + (lane & 15);
                b[ni] = *(const short8*)(Bs + row * 64 + ((g ^ (row & 7)) * 8));
            }
            #pragma unroll
            for (int mi = 0; mi < 4; ++mi)
                #pragma unroll
                for (int ni = 0; ni < 4; ++ni)
                    acc[mi][ni] = __builtin_amdgcn_mfma_f32_16x16x32_bf16(
                        a[mi], b[ni], acc[mi][ni], 0, 0, 0);
        }
    }

    __syncthreads();
    #pragma unroll
    for (int mi = 0; mi < 4; ++mi)
        #pragma unroll
        for (int ni = 0; ni < 4; ++ni) {
            int colL = wc * 64 + ni * 16 + (lane & 15);
            float bv = bias[colL];
            #pragma unroll
            for (int j = 0; j < 4; ++j) {
                int rL = wr * 64 + mi * 16 + ((lane >> 4) << 2) + j;
                float x = fmaxf(acc[mi][ni][j] + bv, 0.0f);
                int c8 = colL >> 3;
                smem[rL * 256 + ((c8 ^ (rL & 7)) * 8) + (colL & 7)] = f2bf(x);
            }
        }
    __syncthreads();
    f32x4 lacc = {0.f, 0.f, 0.f, 0.f};
    int rL = wid * 16 + (lane & 15);
    #pragma unroll
    for (int k0 = 0; k0 < 256; k0 += 32) {
        int c8 = (k0 >> 3) + (lane >> 4);
        short8 a = *(const short8*)(smem + rL * 256 + ((c8 ^ (rL & 7)) * 8));
        short8 b = *(const short8*)(Wc2t + (lane & 15) * 256 + k0 + (lane >> 4) * 8);
        lacc = __builtin_amdgcn_mfma_f32_16x16x32_bf16(a, b, lacc, 0, 0, 0);
    }
    int colL = lane & 15;
    if (colL < 14) {
        float bb = bc2[colL];
        #pragma unroll
        for (int j = 0; j < 4; ++j) {
            int r = m0 + wid * 16 + (lane >> 4) * 4 + j;
            if (r < M)
                __builtin_nontemporal_store(lacc[j] + bb,
                    logits + (size_t)r * 14 + colL);
        }
    }
}

// ---- CSR build ----
__global__ void count_deg(const int* __restrict__ dst, int* __restrict__ deg, int E)
{
    int e = blockIdx.x * blockDim.x + threadIdx.x;
    if (e < E) atomicAdd(&deg[dst[e]], 1);
}

__global__ __launch_bounds__(1024) void scan_part(
    const int* __restrict__ deg, int* __restrict__ off, int* __restrict__ sums, int N)
{
    __shared__ int buf[1024];
    int i = blockIdx.x * 1024 + threadIdx.x;
    int v = (i < N) ? deg[i] : 0;
    buf[threadIdx.x] = v;
    __syncthreads();
    #pragma unroll
    for (int o = 1; o < 1024; o <<= 1) {
        int t = (threadIdx.x >= o) ? buf[threadIdx.x - o] : 0;
        __syncthreads();
        buf[threadIdx.x] += t;
        __syncthreads();
    }
    if (i < N) off[i] = buf[threadIdx.x] - v;
    if (threadIdx.x == 1023) sums[blockIdx.x] = buf[1023];
}

// fused scan_sums + scan_add: each block wave-scans the <=64 block sums
__global__ __launch_bounds__(1024) void scan_add2(
    const int* __restrict__ sums, int* __restrict__ off,
    int* __restrict__ cursor, int N, int nb)
{
    __shared__ int pre[64];
    __shared__ int total_s;
    if (threadIdx.x < 64) {
        int lane = threadIdx.x;
        int v = (lane < nb) ? sums[lane] : 0;
        int incl = v;
        #pragma unroll
        for (int o = 1; o < 64; o <<= 1) {
            int t = __shfl_up(incl, o);
            if (lane >= o) incl += t;
        }
        pre[lane] = incl - v;
        if (lane == 63) total_s = incl;
    }
    __syncthreads();
    int base = pre[blockIdx.x];
    int i = blockIdx.x * 1024 + threadIdx.x;
    if (i < N) {
        int v = off[i] + base;
        off[i] = v;
        cursor[i] = v;
    }
    if (blockIdx.x == 0 && threadIdx.x == 0) off[N] = total_s;
}

__global__ void fill_csr(const int* __restrict__ src, const int* __restrict__ dst,
                         int* __restrict__ cursor, int* __restrict__ csr, int E)
{
    int e = blockIdx.x * blockDim.x + threadIdx.x;
    if (e < E) {
        int p = atomicAdd(&cursor[dst[e]], 1);
        csr[p] = src[e];
    }
}

// ---- conv1 epilogue: h_g1 = relu(mean_nbr(y1.l)+b+y1.r) -> bf16 [N,256] ----
__global__ __launch_bounds__(256) void sage1_gather(
    const unsigned short* __restrict__ y1,
    const int* __restrict__ off, const int* __restrict__ csr,
    const float* __restrict__ b, unsigned short* __restrict__ out, int N)
{
    int lane = threadIdx.x & 63;
    int node = blockIdx.x * 4 + (threadIdx.x >> 6);
    if (node >= N) return;
    int s = off[node], e = off[node + 1];
    int half = lane >> 5, l32 = lane & 31;
    float a[8] = {};
    int p = s + half;
    for (; p + 6 < e; p += 8) {
        int j0 = csr[p],     j1 = csr[p + 2];
        int j2 = csr[p + 4], j3 = csr[p + 6];
        uint4 v0 = *(const uint4*)(y1 + (size_t)j0 * 512 + l32 * 8);
        uint4 v1 = *(const uint4*)(y1 + (size_t)j1 * 512 + l32 * 8);
        uint4 v2 = *(const uint4*)(y1 + (size_t)j2 * 512 + l32 * 8);
        uint4 v3 = *(const uint4*)(y1 + (size_t)j3 * 512 + l32 * 8);
        a[0] += bflo(v0.x); a[1] += bfhi(v0.x); a[2] += bflo(v0.y); a[3] += bfhi(v0.y);
        a[4] += bflo(v0.z); a[5] += bfhi(v0.z); a[6] += bflo(v0.w); a[7] += bfhi(v0.w);
        a[0] += bflo(v1.x); a[1] += bfhi(v1.x); a[2] += bflo(v1.y); a[3] += bfhi(v1.y);
        a[4] += bflo(v1.z); a[5] += bfhi(v1.z); a[6] += bflo(v1.w); a[7] += bfhi(v1.w);
        a[0] += bflo(v2.x); a[1] += bfhi(v2.x); a[2] += bflo(v2.y); a[3] += bfhi(v2.y);
        a[4] += bflo(v2.z); a[5] += bfhi(v2.z); a[6] += bflo(v2.w); a[7] += bfhi(v2.w);
        a[0] += bflo(v3.x); a[1] += bfhi(v3.x); a[2] += bflo(v3.y); a[3] += bfhi(v3.y);
        a[4] += bflo(v3.z); a[5] += bfhi(v3.z); a[6] += bflo(v3.w); a[7] += bfhi(v3.w);
    }
    for (; p + 2 < e; p += 4) {
        int j0 = csr[p], j1 = csr[p + 2];
        uint4 v0 = *(const uint4*)(y1 + (size_t)j0 * 512 + l32 * 8);
        uint4 v1 = *(const uint4*)(y1 + (size_t)j1 * 512 + l32 * 8);
        a[0] += bflo(v0.x); a[1] += bfhi(v0.x); a[2] += bflo(v0.y); a[3] += bfhi(v0.y);
        a[4] += bflo(v0.z); a[5] += bfhi(v0.z); a[6] += bflo(v0.w); a[7] += bfhi(v0.w);
        a[0] += bflo(v1.x); a[1] += bfhi(v1.x); a[2] += bflo(v1.y); a[3] += bfhi(v1.y);
        a[4] += bflo(v1.z); a[5] += bfhi(v1.z); a[6] += bflo(v1.w); a[7] += bfhi(v1.w);
    }
    for (; p < e; p += 2) {
        int j = csr[p];
        uint4 v = *(const uint4*)(y1 + (size_t)j * 512 + l32 * 8);
        a[0] += bflo(v.x); a[1] += bfhi(v.x); a[2] += bflo(v.y); a[3] += bfhi(v.y);
        a[4] += bflo(v.z); a[5] += bfhi(v.z); a[6] += bflo(v.w); a[7] += bfhi(v.w);
    }
    #pragma unroll
    for (int i = 0; i < 8; ++i) a[i] += __shfl_xor(a[i], 32);
    if (half == 0) {
        float inv = (e > s) ? 1.0f / (float)(e - s) : 1.0f;
        uint4 rv = *(const uint4*)(y1 + (size_t)node * 512 + 256 + l32 * 8);
        float4 b0 = ((const float4*)b)[l32 * 2];
        float4 b1 = ((const float4*)b)[l32 * 2 + 1];
        float r[8] = {bflo(rv.x), bfhi(rv.x), bflo(rv.y), bfhi(rv.y),
                      bflo(rv.z), bfhi(rv.z), bflo(rv.w), bfhi(rv.w)};
        float bb[8] = {b0.x, b0.y, b0.z, b0.w, b1.x, b1.y, b1.z, b1.w};
        u32x4 vv;
        #pragma unroll
        for (int i = 0; i < 4; ++i) {
            unsigned int lo = f2bf(fmaxf(a[2*i]   * inv + bb[2*i]   + r[2*i],   0.f));
            unsigned int hi = f2bf(fmaxf(a[2*i+1] * inv + bb[2*i+1] + r[2*i+1], 0.f));
            vv[i] = lo | (hi << 16);
        }
        *(u32x4*)(out + (size_t)node * 256 + l32 * 8) = vv;
    }
}

// ---- conv2 epilogue: h_g = l2norm(mean+b+root) -> bf16 (cls_bf col 384) ----
__global__ __launch_bounds__(256) void sage2_gather_norm(
    const unsigned short* __restrict__ y2,
    const int* __restrict__ off, const int* __restrict__ csr,
    const float* __restrict__ b, unsigned short* __restrict__ outb, int N)
{
    int lane = threadIdx.x & 63;
    int node = blockIdx.x * 4 + (threadIdx.x >> 6);
    if (node >= N) return;
    int s = off[node], e = off[node + 1];
    int grp = lane >> 4, l16 = lane & 15;
    float a[8] = {};
    int p = s + grp;
    for (; p + 4 < e; p += 8) {
        int j0 = csr[p], j1 = csr[p + 4];
        uint4 v0 = *(const uint4*)(y2 + (size_t)j0 * 256 + l16 * 8);
        uint4 v1 = *(const uint4*)(y2 + (size_t)j1 * 256 + l16 * 8);
        a[0] += bflo(v0.x); a[1] += bfhi(v0.x); a[2] += bflo(v0.y); a[3] += bfhi(v0.y);
        a[4] += bflo(v0.z); a[5] += bfhi(v0.z); a[6] += bflo(v0.w); a[7] += bfhi(v0.w);
        a[0] += bflo(v1.x); a[1] += bfhi(v1.x); a[2] += bflo(v1.y); a[3] += bfhi(v1.y);
        a[4] += bflo(v1.z); a[5] += bfhi(v1.z); a[6] += bflo(v1.w); a[7] += bfhi(v1.w);
    }
    for (; p < e; p += 4) {
        int j = csr[p];
        uint4 v = *(const uint4*)(y2 + (size_t)j * 256 + l16 * 8);
        a[0] += bflo(v.x); a[1] += bfhi(v.x); a[2] += bflo(v.y); a[3] += bfhi(v.y);
        a[4] += bflo(v.z); a[5] += bfhi(v.z); a[6] += bflo(v.w); a[7] += bfhi(v.w);
    }
    #pragma unroll
    for (int i = 0; i < 8; ++i) {
        a[i] += __shfl_xor(a[i], 16);
        a[i] += __shfl_xor(a[i], 32);
    }
    if (grp == 0) {
        float inv = (e > s) ? 1.0f / (float)(e - s) : 1.0f;
        uint4 rv = *(const uint4*)(y2 + (size_t)node * 256 + 128 + l16 * 8);
        float4 b0 = ((const float4*)b)[l16 * 2];
        float4 b1 = ((const float4*)b)[l16 * 2 + 1];
        float r[8] = {bflo(rv.x), bfhi(rv.x), bflo(rv.y), bfhi(rv.y),
                      bflo(rv.z), bfhi(rv.z), bflo(rv.w), bfhi(rv.w)};
        float bb[8] = {b0.x, b0.y, b0.z, b0.w, b1.x, b1.y, b1.z, b1.w};
        float h[8];
        float ss = 0.f;
        #pragma unroll
        for (int i = 0; i < 8; ++i) {
            h[i] = a[i] * inv + bb[i] + r[i];
            ss += h[i] * h[i];
        }
        ss += __shfl_xor(ss, 1);
        ss += __shfl_xor(ss, 2);
        ss += __shfl_xor(ss, 4);
        ss += __shfl_xor(ss, 8);
        float sc = 1.0f / fmaxf(sqrtf(ss), 1e-12f);
        u32x4 vv;
        #pragma unroll
        for (int i = 0; i < 4; ++i) {
            unsigned int lo = f2bf(h[2*i] * sc);
            unsigned int hi = f2bf(h[2*i+1] * sc);
            vv[i] = lo | (hi << 16);
        }
        *(u32x4*)(outb + (size_t)node * 512 + l16 * 8) = vv;
    }
}

extern "C" void kernel_launch(void* const* d_in, const int* in_sizes, int n_in,
                              void* d_out, int out_size, void* d_ws, size_t ws_size,
                              hipStream_t stream)
{
    const float* h_v   = (const float*)d_in[0];
    const float* h_t   = (const float*)d_in[1];
    const float* h_tab = (const float*)d_in[2];
    const int*   eidx  = (const int*)d_in[3];
    const float* W1l = (const float*)d_in[4];
    const float* W1r = (const float*)d_in[5];
    const float* b1g = (const float*)d_in[6];
    const float* W2l = (const float*)d_in[7];
    const float* W2r = (const float*)d_in[8];
    const float* b2g = (const float*)d_in[9];
    const float* Wsh = (const float*)d_in[10];
    const float* bsh = (const float*)d_in[11];
    const float* Wst = (const float*)d_in[12];
    const float* bst = (const float*)d_in[13];
    const float* Wstab = (const float*)d_in[14];
    const float* bstab = (const float*)d_in[15];
    const float* Wc1 = (const float*)d_in[16];
    const float* bc1 = (const float*)d_in[17];
    const float* Wc2 = (const float*)d_in[18];
    const float* bc2 = (const float*)d_in[19];

    const int N = in_sizes[0] / 128;      // 50000
    const int E = in_sizes[3] / 2;        // 500000
    const int* src = eidx;
    const int* dst = eidx + E;

    // ---- workspace layout ----
    int* deg    = (int*)d_ws;
    int* off    = deg + N;
    int* cursor = off + N + 1;
    int* csr    = cursor + N;
    int* sums   = csr + E;
    size_t int_bytes = ((size_t)3 * N + 1 + E + 64) * 4;
    unsigned short* Wt = (unsigned short*)((char*)d_ws + ((int_bytes + 255) & ~(size_t)255));
    const int oW1l = 0;                    // 256*384
    const int oW1r = oW1l + 98304;
    const int oW2l = oW1r + 98304;         // 128*256
    const int oW2r = oW2l + 32768;
    const int oWsh = oW2r + 32768;         // 128*128
    const int oWst = oWsh + 16384;
    const int oWstab = oWst + 16384;
    const int oWc1 = oWstab + 16384;       // 256*512
    const int oWc2t = oWc1 + 131072;       // 16*256 (rows 14,15 zero)
    const int wtotal = oWc2t + 4096;

    unsigned short* Xbf   = Wt + wtotal;                  // [N,384]
    unsigned short* bufY  = Xbf + (size_t)N * 384;        // y1 [N,512] -> cls_bf
    unsigned short* bufH  = bufY + (size_t)N * 512;       // hg1 [N,256]
    unsigned short* bufY2 = bufH + (size_t)N * 256;       // y2 [N,256]

    float* out    = (float*)d_out;
    float* logits = out;
    float* z_sh   = out + (size_t)N * 14;
    float* z_t    = z_sh + (size_t)N * 128;
    float* z_tab  = z_t + (size_t)N * 128;

    const int gx = (N + 127) / 128;   // 391
    const int gxp = (gx + 7) & ~7;    // 392: multiple of 8 for XCD decode
    const int nb = (N + 1023) / 1024; // 49

    // ---- merged prep: zero deg + zero Wc2t pad + convert_x + convert_w ----
    WPack p;
    p.w[0] = {W1l, 384, 256, oW1l};     p.w[1] = {W1r, 384, 256, oW1r};
    p.w[2] = {W2l, 256, 128, oW2l};     p.w[3] = {W2r, 256, 128, oW2r};
    p.w[4] = {Wsh, 128, 128, oWsh};     p.w[5] = {Wst, 128, 128, oWst};
    p.w[6] = {Wstab, 128, 128, oWstab}; p.w[7] = {Wc1, 512, 256, oWc1};
    p.w[8] = {Wc2, 256, 14, oWc2t};
    {
        int ndeg16 = (N + 3) / 4;
        int ZB = (ndeg16 + 255) / 256;                 // 50
        int XB = (N * 96 + 255) / 256;                 // 18750
        int total_blocks = ZB + 1 + XB + 9 * 64;
        prep<<<total_blocks, 256, 0, stream>>>(h_v, h_t, h_tab, Xbf, N,
            p, Wt, deg, Wt + oWc2t + 14 * 256);
    }

    // ---- CSR build ----
    count_deg<<<(E + 255) / 256, 256, 0, stream>>>(dst, deg, E);
    scan_part<<<nb, 1024, 0, stream>>>(deg, off, sums, N);
    scan_add2<<<nb, 1024, 0, stream>>>(sums, off, cursor, N, nb);
    fill_csr<<<(E + 255) / 256, 256, 0, stream>>>(src, dst, cursor, csr, E);

    // ---- conv1: [N,384] x [384, 512(l|r)] -> y1 bf16 (4 panels, XCD-local) --
    unsigned short* y1 = bufY;
    {
        GemmP3 g{};
        g.q[0] = {Xbf, 384, Wt + oW1l, nullptr, nullptr, 0, y1, 512};
        gemm4<0, 4><<<dim3(gxp * 4), 256, 0, stream>>>(g, N, 384);
    }

    // ---- conv1 gather -> h_g1 bf16 [N,256] ----
    sage1_gather<<<(N + 3) / 4, 256, 0, stream>>>(y1, off, csr, b1g, bufH, N);

    // ---- conv2: [N,256] x [256, 256(l|r)] -> y2 bf16 (2 panels, XCD-local) --
    {
        GemmP3 g{};
        g.q[0] = {bufH, 256, Wt + oW2l, nullptr, nullptr, 0, bufY2, 256};
        gemm4<0, 2><<<dim3(gxp * 2), 256, 0, stream>>>(g, N, 256);
    }

    // ---- conv2 gather + l2norm -> h_g bf16 (cls_bf col 384) ----
    unsigned short* cls_bf = bufY;  // y1 dead
    sage2_gather_norm<<<(N + 3) / 4, 256, 0, stream>>>(bufY2, off, csr, b2g,
        cls_bf + 384, N);

    // ---- 3 projections in one launch: fp32 -> d_out, bf16 -> cls_bf ----
    {
        GemmP3 g{};
        g.q[0] = {cls_bf + 384, 512, Wt + oWsh,   bsh,   z_sh,  128, cls_bf + 0,   512};
        g.q[1] = {Xbf + 128,    384, Wt + oWst,   bst,   z_t,   128, cls_bf + 128, 512};
        g.q[2] = {Xbf + 256,    384, Wt + oWstab, bstab, z_tab, 128, cls_bf + 256, 512};
        gemm4<1, 1><<<dim3(gxp, 1, 3), 256, 0, stream>>>(g, N, 128);
    }

    // ---- classifier: [N,512]x[512,256] + relu + fused logits ----
    gemm5<<<dim3(gxp), 512, 0, stream>>>(cls_bf, Wt + oWc1, bc1,
        Wt + oWc2t, bc2, logits, N, 512);
}